// Round 8
// baseline (218.088 us; speedup 1.0000x reference)
//
#include <hip/hip_runtime.h>
#include <hip/hip_bf16.h>
#include <string.h>

#define D 256
#define NH 8
#define DH 32
#define NL 4
#define NP 4
#define DFF 1024
#define LTOT 8500

typedef __bf16 bf16x8 __attribute__((ext_vector_type(8)));
typedef float floatx4 __attribute__((ext_vector_type(4)));

__device__ inline unsigned bpack(float a, float b) {
    __hip_bfloat16 ha = __float2bfloat16(a), hb = __float2bfloat16(b);
    unsigned short ua, ub;
    memcpy(&ua, &ha, 2); memcpy(&ub, &hb, 2);
    return (unsigned)ua | ((unsigned)ub << 16);
}

// async 16B global->LDS (wave-uniform LDS dest + lane*16; per-lane global src)
__device__ inline void gload16(const void* g, void* l) {
    __builtin_amdgcn_global_load_lds((const __attribute__((address_space(1))) void*)g,
                                     (__attribute__((address_space(3))) void*)l,
                                     16, 0, 0);
}

// ---------------- transpose+convert 6 weights (736 tiles) + bf16 prep of q/src ----------------
__global__ void transpose_all(const float* W0, const float* W1_, const float* W2_,
                              const float* W3, const float* W4, const float* W5,
                              __hip_bfloat16* T0, __hip_bfloat16* T1, __hip_bfloat16* T2,
                              __hip_bfloat16* T3, __hip_bfloat16* T4, __hip_bfloat16* T5,
                              const float* src, const float* pos,
                              __hip_bfloat16* qb, __hip_bfloat16* srcb) {
    int id = blockIdx.x;
    if (id >= 736) {
        int idx = (id - 736) * 2048 + threadIdx.x * 8;
        if (idx < LTOT * 256) {
            float4 s0 = *(const float4*)(src + idx);
            float4 s1 = *(const float4*)(src + idx + 4);
            float4 p0 = *(const float4*)(pos + idx);
            float4 p1 = *(const float4*)(pos + idx + 4);
            uint4 us, uq;
            us.x = bpack(s0.x, s0.y); us.y = bpack(s0.z, s0.w);
            us.z = bpack(s1.x, s1.y); us.w = bpack(s1.z, s1.w);
            uq.x = bpack(s0.x + p0.x, s0.y + p0.y); uq.y = bpack(s0.z + p0.z, s0.w + p0.w);
            uq.z = bpack(s1.x + p1.x, s1.y + p1.y); uq.w = bpack(s1.z + p1.z, s1.w + p1.w);
            *(uint4*)(srcb + idx) = us;
            *(uint4*)(qb + idx)  = uq;
        }
        return;
    }
    const int cum[7] = {0, 64, 96, 160, 224, 480, 736};
    int mi = 0;
    while (id >= cum[mi + 1]) mi++;
    int lid = id - cum[mi];
    const float* W; __hip_bfloat16* T; int K, N;
    switch (mi) {
        case 0: W = W0; T = T0; K = 256;  N = 256;  break;
        case 1: W = W1_; T = T1; K = 256; N = 128;  break;
        case 2: W = W2_; T = T2; K = 256; N = 256;  break;
        case 3: W = W3; T = T3; K = 256;  N = 256;  break;
        case 4: W = W4; T = T4; K = 256;  N = 1024; break;
        default: W = W5; T = T5; K = 1024; N = 256; break;
    }
    int ntx = N >> 5;
    int n0 = (lid % ntx) * 32, k0 = (lid / ntx) * 32;
    __shared__ float t[32][33];
    int tx = threadIdx.x & 31, ty = threadIdx.x >> 5;
#pragma unroll
    for (int i = 0; i < 32; i += 8)
        t[ty + i][tx] = W[(size_t)(k0 + ty + i) * N + n0 + tx];
    __syncthreads();
#pragma unroll
    for (int i = 0; i < 32; i += 8)
        T[(size_t)(n0 + ty + i) * K + k0 + tx] = __float2bfloat16(t[tx][ty + i]);
}

// ---- fused projection GEMM [Wo | Wa | Wv]: 64x64 tiles, single-buf, max-TLP (r7, unchanged) ----
__global__ __launch_bounds__(256) void proj2(
    const __hip_bfloat16* __restrict__ qb, const __hip_bfloat16* __restrict__ srcb,
    const __hip_bfloat16* __restrict__ WoT, const __hip_bfloat16* __restrict__ WaT,
    const __hip_bfloat16* __restrict__ WvT,
    const float* __restrict__ bo, const float* __restrict__ ba, const float* __restrict__ bv,
    float* __restrict__ locb, float* __restrict__ attnb, __hip_bfloat16* __restrict__ valb,
    int M) {
    constexpr int BM = 64, BN = 64, BK = 64, K = 256;
    __shared__ __align__(16) __hip_bfloat16 sA[BM * BK];
    __shared__ __align__(16) __hip_bfloat16 sB[BN * BK];

    int n0 = blockIdx.x * BN;
    int m0 = blockIdx.y * BM;

    const __hip_bfloat16* BT;
    const __hip_bfloat16* A;
    const float* bias;
    int ncol0, Nout;
    float* Cf; __hip_bfloat16* Cb;
    if (n0 < 256)      { A = qb;   BT = WoT; bias = bo; ncol0 = n0;       Nout = 256; Cf = locb;  Cb = nullptr; }
    else if (n0 < 384) { A = qb;   BT = WaT; bias = ba; ncol0 = n0 - 256; Nout = 128; Cf = attnb; Cb = nullptr; }
    else               { A = srcb; BT = WvT; bias = bv; ncol0 = n0 - 384; Nout = 256; Cf = nullptr; Cb = valb; }

    int tid = threadIdx.x, wave = tid >> 6, lane = tid & 63;
    int wm = (wave >> 1) * 32, wn = (wave & 1) * 32;

    floatx4 acc[2][2];
#pragma unroll
    for (int i = 0; i < 2; i++)
#pragma unroll
        for (int j = 0; j < 2; j++)
#pragma unroll
            for (int e = 0; e < 4; e++) acc[i][j][e] = 0.f;

    int lrow = lane & 15, swz = lrow & 7;
    int scol = ((lane & 7) ^ (lane >> 3)) << 3;

    const __hip_bfloat16* aP[2];
    const __hip_bfloat16* bP[2];
#pragma unroll
    for (int i = 0; i < 2; i++) {
        int ra = m0 + i * 32 + wave * 8 + (lane >> 3); if (ra >= M) ra = M - 1;
        aP[i] = A + (size_t)ra * K + scol;
        int rb = ncol0 + i * 32 + wave * 8 + (lane >> 3);
        bP[i] = BT + (size_t)rb * K + scol;
    }
    int dOff = wave * 1024 + lane * 16;

    for (int k0 = 0; k0 < K; k0 += BK) {
#pragma unroll
        for (int i = 0; i < 2; i++) gload16(aP[i] + k0, (char*)sA + i * 4096 + dOff);
#pragma unroll
        for (int i = 0; i < 2; i++) gload16(bP[i] + k0, (char*)sB + i * 4096 + dOff);
        __syncthreads();
#pragma unroll
        for (int kk = 0; kk < 2; kk++) {
            int co = (((kk << 2) + (lane >> 4)) ^ swz) << 3;
            bf16x8 af[2], bfr[2];
#pragma unroll
            for (int tm = 0; tm < 2; tm++)
                af[tm] = *(const bf16x8*)(&sA[(wm + tm * 16 + lrow) * BK + co]);
#pragma unroll
            for (int tn = 0; tn < 2; tn++)
                bfr[tn] = *(const bf16x8*)(&sB[(wn + tn * 16 + lrow) * BK + co]);
#pragma unroll
            for (int tm = 0; tm < 2; tm++)
#pragma unroll
                for (int tn = 0; tn < 2; tn++)
                    acc[tm][tn] = __builtin_amdgcn_mfma_f32_16x16x32_bf16(af[tm], bfr[tn], acc[tm][tn], 0, 0, 0);
        }
        __syncthreads();
    }

    int lcol = lane & 15, lr4 = (lane >> 4) * 4;
#pragma unroll
    for (int tm = 0; tm < 2; tm++) {
#pragma unroll
        for (int i = 0; i < 4; i++) {
            int row = m0 + wm + tm * 16 + lr4 + i;
            if (row < M) {
#pragma unroll
                for (int tn = 0; tn < 2; tn++) {
                    int col = ncol0 + wn + tn * 16 + lcol;
                    float v = acc[tm][tn][i] + bias[col];
                    if (Cf) Cf[(size_t)row * Nout + col] = v;
                    else    Cb[(size_t)row * Nout + col] = __float2bfloat16(v);
                }
            }
        }
    }
}

// ---- MERGED: deform (16 queries, 2x8 sub-rounds) + attn-out GEMM (K=256) + residual + LN ----
// 512 thr, grid ceil(M/16); LDS ~75KB -> 2 blocks/CU, 16 waves/CU.
__global__ __launch_bounds__(512) void deform_ln(
    const __hip_bfloat16* __restrict__ value,
    const float* __restrict__ locraw,
    const float* __restrict__ logits,
    const float* __restrict__ refp,
    const __hip_bfloat16* __restrict__ BT,   // WoutT [256][256]
    const float* __restrict__ bias,          // bout
    const float* __restrict__ resid,         // src (f32)
    const float* __restrict__ g, const float* __restrict__ be,
    float* __restrict__ outf, __hip_bfloat16* __restrict__ outb,
    int M) {
    __shared__ float wS[8][8][16][4];                        // 16KB
    __shared__ int   aS[8][8][16][4];                        // 16KB
    __shared__ __align__(16) __hip_bfloat16 aobL[16][264];   // 8.25KB, +8 pad -> 2-way banks
    __shared__ __align__(16) __hip_bfloat16 sB[256 * 64];    // 32KB
    __shared__ float psum[8][16], psq[8][16], mS[16], rS[16];

    int tid = threadIdx.x, wave = tid >> 6, lane = tid & 63;
    int m0 = blockIdx.x * 16;

    // ================== deform: 2 sub-rounds of 8 queries ==================
    for (int r = 0; r < 2; r++) {
        int sub = tid >> 6, h = (tid >> 3) & 7, t8 = tid & 7;
        int q = m0 + r * 8 + sub; if (q >= M) q = M - 1;
        {   // phase 1: softmax over 16 logits + sample locations -> wS/aS
            const float* lg = logits + q * 128 + h * 16;
            float l0 = lg[t8], l1 = lg[t8 + 8];
            float mx = fmaxf(l0, l1);
#pragma unroll
            for (int m = 1; m < 8; m <<= 1) mx = fmaxf(mx, __shfl_xor(mx, m, 64));
            float e0 = __expf(l0 - mx), e1 = __expf(l1 - mx);
            float s = e0 + e1;
#pragma unroll
            for (int m = 1; m < 8; m <<= 1) s += __shfl_xor(s, m, 64);
            float inv = 1.f / s;

            const int starts[4] = {0, 6400, 8000, 8400};
#pragma unroll
            for (int j = 0; j < 2; j++) {
                int pp = t8 + 8 * j;
                float a = (j ? e1 : e0) * inv;
                int l = pp >> 2;
                int Wl = 80 >> l;
                float nv = (float)Wl;
                float rx = refp[q * 8 + l * 2 + 0];
                float ry = refp[q * 8 + l * 2 + 1];
                float lx = rx + locraw[q * 256 + h * 32 + pp * 2 + 0] / nv;
                float ly = ry + locraw[q * 256 + h * 32 + pp * 2 + 1] / nv;
                float x = lx * nv - 0.5f;
                float y = ly * nv - 0.5f;
                float x0f = floorf(x), y0f = floorf(y);
                float fx = x - x0f, fy = y - y0f;
                int x0 = (int)x0f, y0 = (int)y0f;
                float wts[4] = {(1.f - fx) * (1.f - fy), fx * (1.f - fy),
                                (1.f - fx) * fy,         fx * fy};
                int st = starts[l];
#pragma unroll
                for (int t = 0; t < 4; t++) {
                    int xi = x0 + (t & 1), yi = y0 + (t >> 1);
                    bool valid = (xi >= 0) & (xi < Wl) & (yi >= 0) & (yi < Wl);
                    int xc = min(max(xi, 0), Wl - 1), yc = min(max(yi, 0), Wl - 1);
                    wS[sub][h][pp][t] = valid ? wts[t] * a : 0.f;
                    aS[sub][h][pp][t] = (st + yc * Wl + xc) * 512 + h * 64;
                }
            }
        }
        __syncthreads();

        {   // phase 2: gather + weighted sum -> aobL row
            int l8 = tid & 7;
            const char* vb = (const char*)value;
            int lo = l8 * 8;
            float a0 = 0.f, a1 = 0.f, a2 = 0.f, a3 = 0.f;
#pragma unroll
            for (int p = 0; p < 16; p++) {
                floatx4 w = *(const floatx4*)&wS[sub][h][p][0];
                int4 av = *(const int4*)&aS[sub][h][p][0];
#pragma unroll
                for (int t = 0; t < 4; t++) {
                    int ad = (t == 0) ? av.x : (t == 1) ? av.y : (t == 2) ? av.z : av.w;
                    uint2 u = *(const uint2*)(vb + ad + lo);
                    float wt = w[t];
                    a0 += wt * __uint_as_float(u.x << 16);
                    a1 += wt * __uint_as_float(u.x & 0xffff0000u);
                    a2 += wt * __uint_as_float(u.y << 16);
                    a3 += wt * __uint_as_float(u.y & 0xffff0000u);
                }
            }
            uint2 o;
            o.x = bpack(a0, a1);
            o.y = bpack(a2, a3);
            int lr = r * 8 + sub;
            *(uint2*)((char*)&aobL[0][0] + lr * 528 + h * 64 + l8 * 8) = o;
        }
        __syncthreads();   // wS/aS reuse next round; aobL complete before GEMM
    }

    // ================== GEMM: out16 = aobL @ WoutT + bias + resid, then LN ==================
    int lrow = lane & 15, swz = lrow & 7, q2 = lane >> 4;
    int scolB = ((tid & 7) ^ ((tid >> 3) & 7)) << 3;
    const __hip_bfloat16* bP[4];
#pragma unroll
    for (int i = 0; i < 4; i++)
        bP[i] = BT + (size_t)(i * 64 + (tid >> 3)) * 256 + scolB;

    floatx4 acc[2];
#pragma unroll
    for (int j = 0; j < 2; j++)
#pragma unroll
        for (int e = 0; e < 4; e++) acc[j][e] = 0.f;

    for (int t = 0; t < 4; t++) {
#pragma unroll
        for (int i = 0; i < 4; i++) gload16(bP[i] + t * 64, (char*)sB + i * 8192 + tid * 16);
        __syncthreads();
#pragma unroll
        for (int kk = 0; kk < 2; kk++) {
            int co = (((kk << 2) + q2) ^ swz) << 3;
            bf16x8 af = *(const bf16x8*)(&aobL[lrow][t * 64 + kk * 32 + q2 * 8]);
            bf16x8 bfr[2];
#pragma unroll
            for (int tn = 0; tn < 2; tn++)
                bfr[tn] = *(const bf16x8*)(&sB[(wave * 32 + tn * 16 + lrow) * 64 + co]);
#pragma unroll
            for (int tn = 0; tn < 2; tn++)
                acc[tn] = __builtin_amdgcn_mfma_f32_16x16x32_bf16(af, bfr[tn], acc[tn], 0, 0, 0);
        }
        __syncthreads();
    }

    int lcol = lane & 15, quad = lane >> 4;
    float v[2][4];
#pragma unroll
    for (int i = 0; i < 4; i++) {
        int row = quad * 4 + i;
        int grow = m0 + row; if (grow >= M) grow = M - 1;
#pragma unroll
        for (int tn = 0; tn < 2; tn++) {
            int col = wave * 32 + tn * 16 + lcol;
            v[tn][i] = acc[tn][i] + bias[col] + resid[(size_t)grow * 256 + col];
        }
    }

#pragma unroll
    for (int i = 0; i < 4; i++) {
        float s = 0.f, s2 = 0.f;
#pragma unroll
        for (int tn = 0; tn < 2; tn++) { float x = v[tn][i]; s += x; s2 += x * x; }
#pragma unroll
        for (int m = 1; m < 16; m <<= 1) {
            s  += __shfl_xor(s, m, 64);
            s2 += __shfl_xor(s2, m, 64);
        }
        if (lcol == 0) {
            int row = quad * 4 + i;
            psum[wave][row] = s;
            psq[wave][row]  = s2;
        }
    }
    __syncthreads();
    if (tid < 16) {
        float s = 0.f, s2 = 0.f;
#pragma unroll
        for (int w = 0; w < 8; w++) { s += psum[w][tid]; s2 += psq[w][tid]; }
        float m = s * (1.f / 256.f);
        float var = fmaxf(s2 * (1.f / 256.f) - m * m, 0.f);
        mS[tid] = m;
        rS[tid] = rsqrtf(var + 1e-5f);
    }
    __syncthreads();

#pragma unroll
    for (int i = 0; i < 4; i++) {
        int row = quad * 4 + i;
        int grow = m0 + row;
        if (grow < M) {
            float m = mS[row], rr = rS[row];
#pragma unroll
            for (int tn = 0; tn < 2; tn++) {
                int col = wave * 32 + tn * 16 + lcol;
                float o = (v[tn][i] - m) * rr * g[col] + be[col];
                outf[(size_t)grow * 256 + col] = o;
                outb[(size_t)grow * 256 + col] = __float2bfloat16(o);
            }
        }
    }
}

// ---- MERGED FFN: out = LN(x1 + relu(x1b@W1+b1)@W2 + b2); H in padded LDS ----
// BM=16, 512 thr, grid ceil(M/16); LDS ~75KB -> 2 blocks/CU, 16 waves/CU.
__global__ __launch_bounds__(512) void ffn(
    const __hip_bfloat16* __restrict__ A,    // x1b [M][256] bf16
    const __hip_bfloat16* __restrict__ W1T,  // [1024][256]
    const float* __restrict__ b1,
    const __hip_bfloat16* __restrict__ W2T,  // [256][1024]
    const float* __restrict__ b2,
    const float* __restrict__ resid,         // x1 [M][256] f32
    const float* __restrict__ g, const float* __restrict__ be,
    float* __restrict__ outf, int M) {
    __shared__ __align__(16) __hip_bfloat16 sAx[16 * 256];   // 8KB  (XOR-swizzled rows)
    __shared__ __align__(16) __hip_bfloat16 H[16 * 1032];    // 33KB (padded rows)
    __shared__ __align__(16) __hip_bfloat16 sB[256 * 64];    // 32KB
    __shared__ float psum[8][16], psq[8][16], mS[16], rS[16];

    int tid = threadIdx.x, wave = tid >> 6, lane = tid & 63;
    int m0 = blockIdx.x * 16;
    int lrow = lane & 15, swz = lrow & 7, q2 = lane >> 4;
    int quad = lane >> 4, lcol = lane & 15;
    int swzA = (lrow & 7) << 3;

    // stage sAx once (512 chunks / 512 thr), source pre-swizzled (rule 21)
    {
        int rr = tid >> 5, cc = tid & 31;
        int gr = m0 + rr; if (gr >= M) gr = M - 1;
        int colel = (cc * 8) ^ ((rr & 7) << 3);
        gload16(A + (size_t)gr * 256 + colel, (char*)sAx + tid * 16);
    }

    int scolB = ((tid & 7) ^ ((tid >> 3) & 7)) << 3;

    // ---- phase A: H = relu(x1b @ W1 + b1), 4 col-chunks of 256 ----
    for (int c = 0; c < 4; c++) {
        const __hip_bfloat16* bP[4];
#pragma unroll
        for (int i = 0; i < 4; i++)
            bP[i] = W1T + (size_t)(c * 256 + i * 64 + (tid >> 3)) * 256 + scolB;

        floatx4 acc[2];
#pragma unroll
        for (int j = 0; j < 2; j++)
#pragma unroll
            for (int e = 0; e < 4; e++) acc[j][e] = 0.f;

        for (int t = 0; t < 4; t++) {
#pragma unroll
            for (int i = 0; i < 4; i++) gload16(bP[i] + t * 64, (char*)sB + i * 8192 + tid * 16);
            __syncthreads();   // c==0,t==0 also drains sAx staging
#pragma unroll
            for (int kk = 0; kk < 2; kk++) {
                int co = (((kk << 2) + q2) ^ swz) << 3;
                bf16x8 af = *(const bf16x8*)(&sAx[lrow * 256 + ((t * 64 + kk * 32 + q2 * 8) ^ swzA)]);
                bf16x8 bfr[2];
#pragma unroll
                for (int tn = 0; tn < 2; tn++)
                    bfr[tn] = *(const bf16x8*)(&sB[(wave * 32 + tn * 16 + lrow) * 64 + co]);
#pragma unroll
                for (int tn = 0; tn < 2; tn++)
                    acc[tn] = __builtin_amdgcn_mfma_f32_16x16x32_bf16(af, bfr[tn], acc[tn], 0, 0, 0);
            }
            __syncthreads();
        }

        // write H chunk (bias + relu) to padded LDS
#pragma unroll
        for (int i = 0; i < 4; i++) {
            int row = quad * 4 + i;
#pragma unroll
            for (int tn = 0; tn < 2; tn++) {
                int col = c * 256 + wave * 32 + tn * 16 + lcol;
                float v = acc[tn][i] + b1[col];
                H[row * 1032 + col] = __float2bfloat16(fmaxf(v, 0.f));
            }
        }
        // no barrier needed: next sB stage is a different region; H reads happen after a barrier
    }

    // ---- phase B: out16 = H @ W2T (K=1024) + b2 + resid, LN ----
    const __hip_bfloat16* bP2[4];
#pragma unroll
    for (int i = 0; i < 4; i++)
        bP2[i] = W2T + (size_t)(i * 64 + (tid >> 3)) * 1024 + scolB;

    floatx4 acc2[2];
#pragma unroll
    for (int j = 0; j < 2; j++)
#pragma unroll
        for (int e = 0; e < 4; e++) acc2[j][e] = 0.f;

    for (int t = 0; t < 16; t++) {
#pragma unroll
        for (int i = 0; i < 4; i++) gload16(bP2[i] + t * 64, (char*)sB + i * 8192 + tid * 16);
        __syncthreads();   // also makes all H writes visible (first iter)
#pragma unroll
        for (int kk = 0; kk < 2; kk++) {
            int co = (((kk << 2) + q2) ^ swz) << 3;
            bf16x8 af = *(const bf16x8*)(&H[lrow * 1032 + t * 64 + kk * 32 + q2 * 8]);
            bf16x8 bfr[2];
#pragma unroll
            for (int tn = 0; tn < 2; tn++)
                bfr[tn] = *(const bf16x8*)(&sB[(wave * 32 + tn * 16 + lrow) * 64 + co]);
#pragma unroll
            for (int tn = 0; tn < 2; tn++)
                acc2[tn] = __builtin_amdgcn_mfma_f32_16x16x32_bf16(af, bfr[tn], acc2[tn], 0, 0, 0);
        }
        __syncthreads();
    }

    float v[2][4];
#pragma unroll
    for (int i = 0; i < 4; i++) {
        int row = quad * 4 + i;
        int grow = m0 + row; if (grow >= M) grow = M - 1;
#pragma unroll
        for (int tn = 0; tn < 2; tn++) {
            int col = wave * 32 + tn * 16 + lcol;
            v[tn][i] = acc2[tn][i] + b2[col] + resid[(size_t)grow * 256 + col];
        }
    }

#pragma unroll
    for (int i = 0; i < 4; i++) {
        float s = 0.f, s2 = 0.f;
#pragma unroll
        for (int tn = 0; tn < 2; tn++) { float x = v[tn][i]; s += x; s2 += x * x; }
#pragma unroll
        for (int m = 1; m < 16; m <<= 1) {
            s  += __shfl_xor(s, m, 64);
            s2 += __shfl_xor(s2, m, 64);
        }
        if (lcol == 0) {
            int row = quad * 4 + i;
            psum[wave][row] = s;
            psq[wave][row]  = s2;
        }
    }
    __syncthreads();
    if (tid < 16) {
        float s = 0.f, s2 = 0.f;
#pragma unroll
        for (int w = 0; w < 8; w++) { s += psum[w][tid]; s2 += psq[w][tid]; }
        float m = s * (1.f / 256.f);
        float var = fmaxf(s2 * (1.f / 256.f) - m * m, 0.f);
        mS[tid] = m;
        rS[tid] = rsqrtf(var + 1e-5f);
    }
    __syncthreads();

#pragma unroll
    for (int i = 0; i < 4; i++) {
        int row = quad * 4 + i;
        int grow = m0 + row;
        if (grow < M) {
            float m = mS[row], rr = rS[row];
#pragma unroll
            for (int tn = 0; tn < 2; tn++) {
                int col = wave * 32 + tn * 16 + lcol;
                outf[(size_t)grow * 256 + col] = (v[tn][i] - m) * rr * g[col] + be[col];
            }
        }
    }
}

extern "C" void kernel_launch(void* const* d_in, const int* in_sizes, int n_in,
                              void* d_out, int out_size, void* d_ws, size_t ws_size,
                              hipStream_t stream) {
    const float* src  = (const float*)d_in[0];
    const float* pos  = (const float*)d_in[1];
    const float* refp = (const float*)d_in[2];
    const float* Wo   = (const float*)d_in[6];
    const float* bo   = (const float*)d_in[7];
    const float* Wa   = (const float*)d_in[8];
    const float* ba   = (const float*)d_in[9];
    const float* Wv   = (const float*)d_in[10];
    const float* bv   = (const float*)d_in[11];
    const float* Wout = (const float*)d_in[12];
    const float* bout = (const float*)d_in[13];
    const float* W1   = (const float*)d_in[14];
    const float* b1   = (const float*)d_in[15];
    const float* W2   = (const float*)d_in[16];
    const float* b2   = (const float*)d_in[17];
    const float* g1   = (const float*)d_in[18];
    const float* be1  = (const float*)d_in[19];
    const float* g2   = (const float*)d_in[20];
    const float* be2  = (const float*)d_in[21];
    float* out = (float*)d_out;
    char* ws = (char*)d_ws;

    // ---- workspace layout (bytes) ----
    __hip_bfloat16* WoT   = (__hip_bfloat16*)(ws + 0);         //  131072
    __hip_bfloat16* WaT   = (__hip_bfloat16*)(ws + 131072);    //   65536
    __hip_bfloat16* WvT   = (__hip_bfloat16*)(ws + 196608);    //  131072
    __hip_bfloat16* WoutT = (__hip_bfloat16*)(ws + 327680);    //  131072
    __hip_bfloat16* W1T   = (__hip_bfloat16*)(ws + 458752);    //  524288
    __hip_bfloat16* W2T   = (__hip_bfloat16*)(ws + 983040);    //  524288
    float*          locb  = (float*)(ws + 1507328);            // 8704000
    float*          attnb = (float*)(ws + 10211328);           // 4352000
    __hip_bfloat16* valb  = (__hip_bfloat16*)(ws + 14563328);  // 4352000
    float*          x1    = (float*)(ws + 23267328);           // 8704000
    __hip_bfloat16* x1b   = (__hip_bfloat16*)(ws + 31971328);  // 4352000
    __hip_bfloat16* qb    = (__hip_bfloat16*)(ws + 36323328);            // 4352000
    __hip_bfloat16* srcb  = (__hip_bfloat16*)(ws + 36323328 + 4352000);  // 4352000

    transpose_all<<<736 + 1063, 256, 0, stream>>>(Wo, Wa, Wv, Wout, W1, W2,
                                                  WoT, WaT, WvT, WoutT, W1T, W2T,
                                                  src, pos, qb, srcb);

    proj2<<<dim3(10, 133), 256, 0, stream>>>(qb, srcb, WoT, WaT, WvT, bo, ba, bv,
                                             locb, attnb, valb, LTOT);

    deform_ln<<<532, 512, 0, stream>>>(valb, locb, attnb, refp, WoutT, bout,
                                       src, g1, be1, x1, x1b, LTOT);

    ffn<<<532, 512, 0, stream>>>(x1b, W1T, b1, W2T, b2, x1, g2, be2, out, LTOT);
}

// Round 9
// 206.758 us; speedup vs baseline: 1.0548x; 1.0548x over previous
//
#include <hip/hip_runtime.h>
#include <hip/hip_bf16.h>
#include <string.h>

#define D 256
#define NH 8
#define DH 32
#define NL 4
#define NP 4
#define DFF 1024
#define LTOT 8500

typedef __bf16 bf16x8 __attribute__((ext_vector_type(8)));
typedef float floatx4 __attribute__((ext_vector_type(4)));

__device__ inline unsigned bpack(float a, float b) {
    __hip_bfloat16 ha = __float2bfloat16(a), hb = __float2bfloat16(b);
    unsigned short ua, ub;
    memcpy(&ua, &ha, 2); memcpy(&ub, &hb, 2);
    return (unsigned)ua | ((unsigned)ub << 16);
}

// async 16B global->LDS (wave-uniform LDS dest + lane*16; per-lane global src)
__device__ inline void gload16(const void* g, void* l) {
    __builtin_amdgcn_global_load_lds((const __attribute__((address_space(1))) void*)g,
                                     (__attribute__((address_space(3))) void*)l,
                                     16, 0, 0);
}

// ---------------- transpose+convert 6 weights (736 tiles) + bf16 prep of q/src ----------------
__global__ void transpose_all(const float* W0, const float* W1_, const float* W2_,
                              const float* W3, const float* W4, const float* W5,
                              __hip_bfloat16* T0, __hip_bfloat16* T1, __hip_bfloat16* T2,
                              __hip_bfloat16* T3, __hip_bfloat16* T4, __hip_bfloat16* T5,
                              const float* src, const float* pos,
                              __hip_bfloat16* qb, __hip_bfloat16* srcb) {
    int id = blockIdx.x;
    if (id >= 736) {
        int idx = (id - 736) * 2048 + threadIdx.x * 8;
        if (idx < LTOT * 256) {
            float4 s0 = *(const float4*)(src + idx);
            float4 s1 = *(const float4*)(src + idx + 4);
            float4 p0 = *(const float4*)(pos + idx);
            float4 p1 = *(const float4*)(pos + idx + 4);
            uint4 us, uq;
            us.x = bpack(s0.x, s0.y); us.y = bpack(s0.z, s0.w);
            us.z = bpack(s1.x, s1.y); us.w = bpack(s1.z, s1.w);
            uq.x = bpack(s0.x + p0.x, s0.y + p0.y); uq.y = bpack(s0.z + p0.z, s0.w + p0.w);
            uq.z = bpack(s1.x + p1.x, s1.y + p1.y); uq.w = bpack(s1.z + p1.z, s1.w + p1.w);
            *(uint4*)(srcb + idx) = us;
            *(uint4*)(qb + idx)  = uq;
        }
        return;
    }
    const int cum[7] = {0, 64, 96, 160, 224, 480, 736};
    int mi = 0;
    while (id >= cum[mi + 1]) mi++;
    int lid = id - cum[mi];
    const float* W; __hip_bfloat16* T; int K, N;
    switch (mi) {
        case 0: W = W0; T = T0; K = 256;  N = 256;  break;
        case 1: W = W1_; T = T1; K = 256; N = 128;  break;
        case 2: W = W2_; T = T2; K = 256; N = 256;  break;
        case 3: W = W3; T = T3; K = 256;  N = 256;  break;
        case 4: W = W4; T = T4; K = 256;  N = 1024; break;
        default: W = W5; T = T5; K = 1024; N = 256; break;
    }
    int ntx = N >> 5;
    int n0 = (lid % ntx) * 32, k0 = (lid / ntx) * 32;
    __shared__ float t[32][33];
    int tx = threadIdx.x & 31, ty = threadIdx.x >> 5;
#pragma unroll
    for (int i = 0; i < 32; i += 8)
        t[ty + i][tx] = W[(size_t)(k0 + ty + i) * N + n0 + tx];
    __syncthreads();
#pragma unroll
    for (int i = 0; i < 32; i += 8)
        T[(size_t)(n0 + ty + i) * K + k0 + tx] = __float2bfloat16(t[tx][ty + i]);
}

// ---- 64x64 bf16 GEMM, BK=64, swizzled gload_lds, single-buf, max-TLP (r7, unchanged) ----
__global__ __launch_bounds__(256) void gemm_t(
    const __hip_bfloat16* __restrict__ A, const __hip_bfloat16* __restrict__ BT,
    const float* __restrict__ bias, float* __restrict__ Cf, __hip_bfloat16* __restrict__ Cb,
    int M, int N, int K, int relu) {
    constexpr int BM = 64, BN = 64, BK = 64;
    __shared__ __align__(16) __hip_bfloat16 sA[BM * BK];
    __shared__ __align__(16) __hip_bfloat16 sB[BN * BK];

    int tid = threadIdx.x, wave = tid >> 6, lane = tid & 63;
    int m0 = blockIdx.y * BM, n0 = blockIdx.x * BN;
    int wm = (wave >> 1) * 32, wn = (wave & 1) * 32;

    floatx4 acc[2][2];
#pragma unroll
    for (int i = 0; i < 2; i++)
#pragma unroll
        for (int j = 0; j < 2; j++)
#pragma unroll
            for (int e = 0; e < 4; e++) acc[i][j][e] = 0.f;

    int lrow = lane & 15, swz = lrow & 7;
    int scol = ((lane & 7) ^ (lane >> 3)) << 3;

    const __hip_bfloat16* aP[2];
    const __hip_bfloat16* bP[2];
#pragma unroll
    for (int i = 0; i < 2; i++) {
        int ra = m0 + i * 32 + wave * 8 + (lane >> 3); if (ra >= M) ra = M - 1;
        aP[i] = A + (size_t)ra * K + scol;
        int rb = n0 + i * 32 + wave * 8 + (lane >> 3);
        bP[i] = BT + (size_t)rb * K + scol;
    }
    int dOff = wave * 1024 + lane * 16;

    for (int k0 = 0; k0 < K; k0 += BK) {
#pragma unroll
        for (int i = 0; i < 2; i++) gload16(aP[i] + k0, (char*)sA + i * 4096 + dOff);
#pragma unroll
        for (int i = 0; i < 2; i++) gload16(bP[i] + k0, (char*)sB + i * 4096 + dOff);
        __syncthreads();
#pragma unroll
        for (int kk = 0; kk < 2; kk++) {
            int co = (((kk << 2) + (lane >> 4)) ^ swz) << 3;
            bf16x8 af[2], bfr[2];
#pragma unroll
            for (int tm = 0; tm < 2; tm++)
                af[tm] = *(const bf16x8*)(&sA[(wm + tm * 16 + lrow) * BK + co]);
#pragma unroll
            for (int tn = 0; tn < 2; tn++)
                bfr[tn] = *(const bf16x8*)(&sB[(wn + tn * 16 + lrow) * BK + co]);
#pragma unroll
            for (int tm = 0; tm < 2; tm++)
#pragma unroll
                for (int tn = 0; tn < 2; tn++)
                    acc[tm][tn] = __builtin_amdgcn_mfma_f32_16x16x32_bf16(af[tm], bfr[tn], acc[tm][tn], 0, 0, 0);
        }
        __syncthreads();
    }

    int lcol = lane & 15, lr4 = (lane >> 4) * 4;
#pragma unroll
    for (int tm = 0; tm < 2; tm++) {
#pragma unroll
        for (int i = 0; i < 4; i++) {
            int row = m0 + wm + tm * 16 + lr4 + i;
            if (row < M) {
#pragma unroll
                for (int tn = 0; tn < 2; tn++) {
                    int col = n0 + wn + tn * 16 + lcol;
                    float v = acc[tm][tn][i] + bias[col];
                    if (relu) v = fmaxf(v, 0.f);
                    if (Cf) Cf[(size_t)row * N + col] = v;
                    if (Cb) Cb[(size_t)row * N + col] = __float2bfloat16(v);
                }
            }
        }
    }
}

// ---- fused projection GEMM [Wo | Wa | Wv]: 64x64 tiles, max-TLP (r7, unchanged) ----
__global__ __launch_bounds__(256) void proj2(
    const __hip_bfloat16* __restrict__ qb, const __hip_bfloat16* __restrict__ srcb,
    const __hip_bfloat16* __restrict__ WoT, const __hip_bfloat16* __restrict__ WaT,
    const __hip_bfloat16* __restrict__ WvT,
    const float* __restrict__ bo, const float* __restrict__ ba, const float* __restrict__ bv,
    float* __restrict__ locb, float* __restrict__ attnb, __hip_bfloat16* __restrict__ valb,
    int M) {
    constexpr int BM = 64, BN = 64, BK = 64, K = 256;
    __shared__ __align__(16) __hip_bfloat16 sA[BM * BK];
    __shared__ __align__(16) __hip_bfloat16 sB[BN * BK];

    int n0 = blockIdx.x * BN;
    int m0 = blockIdx.y * BM;

    const __hip_bfloat16* BT;
    const __hip_bfloat16* A;
    const float* bias;
    int ncol0, Nout;
    float* Cf; __hip_bfloat16* Cb;
    if (n0 < 256)      { A = qb;   BT = WoT; bias = bo; ncol0 = n0;       Nout = 256; Cf = locb;  Cb = nullptr; }
    else if (n0 < 384) { A = qb;   BT = WaT; bias = ba; ncol0 = n0 - 256; Nout = 128; Cf = attnb; Cb = nullptr; }
    else               { A = srcb; BT = WvT; bias = bv; ncol0 = n0 - 384; Nout = 256; Cf = nullptr; Cb = valb; }

    int tid = threadIdx.x, wave = tid >> 6, lane = tid & 63;
    int wm = (wave >> 1) * 32, wn = (wave & 1) * 32;

    floatx4 acc[2][2];
#pragma unroll
    for (int i = 0; i < 2; i++)
#pragma unroll
        for (int j = 0; j < 2; j++)
#pragma unroll
            for (int e = 0; e < 4; e++) acc[i][j][e] = 0.f;

    int lrow = lane & 15, swz = lrow & 7;
    int scol = ((lane & 7) ^ (lane >> 3)) << 3;

    const __hip_bfloat16* aP[2];
    const __hip_bfloat16* bP[2];
#pragma unroll
    for (int i = 0; i < 2; i++) {
        int ra = m0 + i * 32 + wave * 8 + (lane >> 3); if (ra >= M) ra = M - 1;
        aP[i] = A + (size_t)ra * K + scol;
        int rb = ncol0 + i * 32 + wave * 8 + (lane >> 3);
        bP[i] = BT + (size_t)rb * K + scol;
    }
    int dOff = wave * 1024 + lane * 16;

    for (int k0 = 0; k0 < K; k0 += BK) {
#pragma unroll
        for (int i = 0; i < 2; i++) gload16(aP[i] + k0, (char*)sA + i * 4096 + dOff);
#pragma unroll
        for (int i = 0; i < 2; i++) gload16(bP[i] + k0, (char*)sB + i * 4096 + dOff);
        __syncthreads();
#pragma unroll
        for (int kk = 0; kk < 2; kk++) {
            int co = (((kk << 2) + (lane >> 4)) ^ swz) << 3;
            bf16x8 af[2], bfr[2];
#pragma unroll
            for (int tm = 0; tm < 2; tm++)
                af[tm] = *(const bf16x8*)(&sA[(wm + tm * 16 + lrow) * BK + co]);
#pragma unroll
            for (int tn = 0; tn < 2; tn++)
                bfr[tn] = *(const bf16x8*)(&sB[(wn + tn * 16 + lrow) * BK + co]);
#pragma unroll
            for (int tm = 0; tm < 2; tm++)
#pragma unroll
                for (int tn = 0; tn < 2; tn++)
                    acc[tm][tn] = __builtin_amdgcn_mfma_f32_16x16x32_bf16(af[tm], bfr[tn], acc[tm][tn], 0, 0, 0);
        }
        __syncthreads();
    }

    int lcol = lane & 15, lr4 = (lane >> 4) * 4;
#pragma unroll
    for (int tm = 0; tm < 2; tm++) {
#pragma unroll
        for (int i = 0; i < 4; i++) {
            int row = m0 + wm + tm * 16 + lr4 + i;
            if (row < M) {
#pragma unroll
                for (int tn = 0; tn < 2; tn++) {
                    int col = ncol0 + wn + tn * 16 + lcol;
                    float v = acc[tm][tn][i] + bias[col];
                    if (Cf) Cf[(size_t)row * Nout + col] = v;
                    else    Cb[(size_t)row * Nout + col] = __float2bfloat16(v);
                }
            }
        }
    }
}

// ---------------- deform core: 4 queries/block, full-TLP grid (r7, unchanged) ----------------
__global__ __launch_bounds__(256) void deform(const __hip_bfloat16* __restrict__ value,
                                              const float* __restrict__ locraw,
                                              const float* __restrict__ logits,
                                              const float* __restrict__ refp,
                                              __hip_bfloat16* __restrict__ out) {
    __shared__ float wS[4][8][16][4];
    __shared__ int   aS[4][8][16][4];
    int tid = threadIdx.x;
    int q0 = blockIdx.x * 4;

    {   // phase 1
        int sub = tid >> 6, h = (tid >> 3) & 7, t8 = tid & 7;
        int q = q0 + sub;
        const float* lg = logits + q * 128 + h * 16;
        float l0 = lg[t8], l1 = lg[t8 + 8];
        float mx = fmaxf(l0, l1);
#pragma unroll
        for (int m = 1; m < 8; m <<= 1) mx = fmaxf(mx, __shfl_xor(mx, m, 64));
        float e0 = __expf(l0 - mx), e1 = __expf(l1 - mx);
        float s = e0 + e1;
#pragma unroll
        for (int m = 1; m < 8; m <<= 1) s += __shfl_xor(s, m, 64);
        float inv = 1.f / s;

        const int starts[4] = {0, 6400, 8000, 8400};
#pragma unroll
        for (int j = 0; j < 2; j++) {
            int pp = t8 + 8 * j;
            float a = (j ? e1 : e0) * inv;
            int l = pp >> 2;
            int Wl = 80 >> l;
            float nv = (float)Wl;
            float rx = refp[q * 8 + l * 2 + 0];
            float ry = refp[q * 8 + l * 2 + 1];
            float lx = rx + locraw[q * 256 + h * 32 + pp * 2 + 0] / nv;
            float ly = ry + locraw[q * 256 + h * 32 + pp * 2 + 1] / nv;
            float x = lx * nv - 0.5f;
            float y = ly * nv - 0.5f;
            float x0f = floorf(x), y0f = floorf(y);
            float fx = x - x0f, fy = y - y0f;
            int x0 = (int)x0f, y0 = (int)y0f;
            float wts[4] = {(1.f - fx) * (1.f - fy), fx * (1.f - fy),
                            (1.f - fx) * fy,         fx * fy};
            int st = starts[l];
#pragma unroll
            for (int t = 0; t < 4; t++) {
                int xi = x0 + (t & 1), yi = y0 + (t >> 1);
                bool valid = (xi >= 0) & (xi < Wl) & (yi >= 0) & (yi < Wl);
                int xc = min(max(xi, 0), Wl - 1), yc = min(max(yi, 0), Wl - 1);
                wS[sub][h][pp][t] = valid ? wts[t] * a : 0.f;
                aS[sub][h][pp][t] = (st + yc * Wl + xc) * 512 + h * 64;
            }
        }
    }
    __syncthreads();

    // phase 2: tid = sub*64 + h*8 + l8
    int sub = tid >> 6, h = (tid >> 3) & 7, l8 = tid & 7;
    int q = q0 + sub;
    const char* vb = (const char*)value;
    int lo = l8 * 8;
    float a0 = 0.f, a1 = 0.f, a2 = 0.f, a3 = 0.f;
#pragma unroll
    for (int p = 0; p < 16; p++) {
        floatx4 w = *(const floatx4*)&wS[sub][h][p][0];
        int4 av = *(const int4*)&aS[sub][h][p][0];
#pragma unroll
        for (int t = 0; t < 4; t++) {
            int ad = (t == 0) ? av.x : (t == 1) ? av.y : (t == 2) ? av.z : av.w;
            uint2 u = *(const uint2*)(vb + ad + lo);
            float wt = w[t];
            a0 += wt * __uint_as_float(u.x << 16);
            a1 += wt * __uint_as_float(u.x & 0xffff0000u);
            a2 += wt * __uint_as_float(u.y << 16);
            a3 += wt * __uint_as_float(u.y & 0xffff0000u);
        }
    }
    uint2 o;
    o.x = bpack(a0, a1);
    o.y = bpack(a2, a3);
    *(uint2*)((char*)out + q * 512 + h * 64 + l8 * 8) = o;
}

// ---- GEMM (N=256) + bias + residual + LayerNorm; 1024 thr, 16 waves x one 16-col strip ----
// BM=16 -> grid 532, 16 waves/block -> 8512 waves ~ 100% machine fill. LDS ~37KB, 2 blocks/CU.
__global__ __launch_bounds__(1024) void gemm_ln(
    const __hip_bfloat16* __restrict__ A, const __hip_bfloat16* __restrict__ BT,
    const float* __restrict__ bias, const float* __restrict__ resid,
    const float* __restrict__ g, const float* __restrict__ be,
    float* __restrict__ outf, __hip_bfloat16* __restrict__ outb,
    int M, int K) {
    constexpr int BM = 16, BK = 64;
    __shared__ __align__(16) __hip_bfloat16 sA[BM * BK];    //  2KB
    __shared__ __align__(16) __hip_bfloat16 sB[256 * BK];   // 32KB
    __shared__ float psum[16][16], psq[16][16], mS[16], rS[16];

    int tid = threadIdx.x;
    int wave = tid >> 6, lane = tid & 63;
    int m0 = blockIdx.x * BM;

    floatx4 acc;
#pragma unroll
    for (int e = 0; e < 4; e++) acc[e] = 0.f;

    int lrow = lane & 15, swz = lrow & 7, q2 = lane >> 4;

    // staging: swizzled source col, same formula both A and B (row&7 == (tid>>3)&7)
    int scol = ((tid & 7) ^ ((tid >> 3) & 7)) << 3;
    // A: 128 chunks (tid<128): row = tid>>3 in 0..15
    int grA = m0 + ((tid >> 3) & 15); if (grA >= M) grA = M - 1;
    const __hip_bfloat16* aP = A + (size_t)grA * K + scol;
    // B: 2048 chunks: ci = i*1024 + tid; row = i*128 + (tid>>3)
    const __hip_bfloat16* bP[2];
#pragma unroll
    for (int i = 0; i < 2; i++)
        bP[i] = BT + (size_t)(i * 128 + (tid >> 3)) * K + scol;

    for (int k0 = 0; k0 < K; k0 += BK) {
        if (tid < 128) gload16(aP + k0, (char*)sA + tid * 16);
#pragma unroll
        for (int i = 0; i < 2; i++) gload16(bP[i] + k0, (char*)sB + i * 16384 + tid * 16);
        __syncthreads();
#pragma unroll
        for (int kk = 0; kk < 2; kk++) {
            int co = (((kk << 2) + q2) ^ swz) << 3;
            bf16x8 af = *(const bf16x8*)(&sA[lrow * BK + co]);
            bf16x8 bfr = *(const bf16x8*)(&sB[(wave * 16 + lrow) * BK + co]);
            acc = __builtin_amdgcn_mfma_f32_16x16x32_bf16(af, bfr, acc, 0, 0, 0);
        }
        __syncthreads();
    }

    int lcol = lane & 15, quad = lane >> 4;
    int col = wave * 16 + lcol;
    float v[4];
#pragma unroll
    for (int i = 0; i < 4; i++) {
        int row = quad * 4 + i;
        int grow = m0 + row; if (grow >= M) grow = M - 1;
        v[i] = acc[i] + bias[col] + resid[(size_t)grow * 256 + col];
    }

#pragma unroll
    for (int i = 0; i < 4; i++) {
        float s = v[i], s2 = v[i] * v[i];
#pragma unroll
        for (int m = 1; m < 16; m <<= 1) {
            s  += __shfl_xor(s, m, 64);
            s2 += __shfl_xor(s2, m, 64);
        }
        if (lcol == 0) {
            int row = quad * 4 + i;
            psum[wave][row] = s;
            psq[wave][row]  = s2;
        }
    }
    __syncthreads();
    if (tid < 16) {
        float s = 0.f, s2 = 0.f;
#pragma unroll
        for (int w = 0; w < 16; w++) { s += psum[w][tid]; s2 += psq[w][tid]; }
        float m = s * (1.f / 256.f);
        float var = fmaxf(s2 * (1.f / 256.f) - m * m, 0.f);
        mS[tid] = m;
        rS[tid] = rsqrtf(var + 1e-5f);
    }
    __syncthreads();

#pragma unroll
    for (int i = 0; i < 4; i++) {
        int row = quad * 4 + i;
        int grow = m0 + row;
        if (grow < M) {
            float m = mS[row], r = rS[row];
            float o = (v[i] - m) * r * g[col] + be[col];
            outf[(size_t)grow * 256 + col] = o;
            if (outb) outb[(size_t)grow * 256 + col] = __float2bfloat16(o);
        }
    }
}

extern "C" void kernel_launch(void* const* d_in, const int* in_sizes, int n_in,
                              void* d_out, int out_size, void* d_ws, size_t ws_size,
                              hipStream_t stream) {
    const float* src  = (const float*)d_in[0];
    const float* pos  = (const float*)d_in[1];
    const float* refp = (const float*)d_in[2];
    const float* Wo   = (const float*)d_in[6];
    const float* bo   = (const float*)d_in[7];
    const float* Wa   = (const float*)d_in[8];
    const float* ba   = (const float*)d_in[9];
    const float* Wv   = (const float*)d_in[10];
    const float* bv   = (const float*)d_in[11];
    const float* Wout = (const float*)d_in[12];
    const float* bout = (const float*)d_in[13];
    const float* W1   = (const float*)d_in[14];
    const float* b1   = (const float*)d_in[15];
    const float* W2   = (const float*)d_in[16];
    const float* b2   = (const float*)d_in[17];
    const float* g1   = (const float*)d_in[18];
    const float* be1  = (const float*)d_in[19];
    const float* g2   = (const float*)d_in[20];
    const float* be2  = (const float*)d_in[21];
    float* out = (float*)d_out;
    char* ws = (char*)d_ws;

    // ---- workspace layout (bytes) ----
    __hip_bfloat16* WoT   = (__hip_bfloat16*)(ws + 0);         //  131072
    __hip_bfloat16* WaT   = (__hip_bfloat16*)(ws + 131072);    //   65536
    __hip_bfloat16* WvT   = (__hip_bfloat16*)(ws + 196608);    //  131072
    __hip_bfloat16* WoutT = (__hip_bfloat16*)(ws + 327680);    //  131072
    __hip_bfloat16* W1T   = (__hip_bfloat16*)(ws + 458752);    //  524288
    __hip_bfloat16* W2T   = (__hip_bfloat16*)(ws + 983040);    //  524288
    float*          locb  = (float*)(ws + 1507328);            // 8704000
    float*          attnb = (float*)(ws + 10211328);           // 4352000
    __hip_bfloat16* valb  = (__hip_bfloat16*)(ws + 14563328);  // 4352000
    __hip_bfloat16* aob   = (__hip_bfloat16*)(ws + 18915328);  // 4352000
    float*          x1    = (float*)(ws + 23267328);           // 8704000
    __hip_bfloat16* x1b   = (__hip_bfloat16*)(ws + 31971328);  // 4352000
    __hip_bfloat16* hb    = (__hip_bfloat16*)(ws + 36323328);  // 17408000  (end ~53.7 MB)
    // qb/srcb overlap hb's region: dead once proj2 completes, before FFN1 writes hb
    __hip_bfloat16* qb    = (__hip_bfloat16*)(ws + 36323328);            // 4352000
    __hip_bfloat16* srcb  = (__hip_bfloat16*)(ws + 36323328 + 4352000);  // 4352000

    transpose_all<<<736 + 1063, 256, 0, stream>>>(Wo, Wa, Wv, Wout, W1, W2,
                                                  WoT, WaT, WvT, WoutT, W1T, W2T,
                                                  src, pos, qb, srcb);

    proj2<<<dim3(10, 133), 256, 0, stream>>>(qb, srcb, WoT, WaT, WvT, bo, ba, bv,
                                             locb, attnb, valb, LTOT);

    deform<<<2125, 256, 0, stream>>>(valb, locb, attnb, refp, aob);

    gemm_ln<<<532, 1024, 0, stream>>>(aob, WoutT, bout, src, g1, be1, x1, x1b, LTOT, 256);

    gemm_t<<<dim3(16, 133), 256, 0, stream>>>(x1b, W1T, b1, nullptr, hb, LTOT, 1024, 256, 1);

    gemm_ln<<<532, 1024, 0, stream>>>(hb, W2T, b2, x1, g2, be2, out, nullptr, LTOT, 1024);
}

// Round 10
// 196.469 us; speedup vs baseline: 1.1100x; 1.0524x over previous
//
#include <hip/hip_runtime.h>
#include <hip/hip_bf16.h>
#include <string.h>

#define D 256
#define NH 8
#define DH 32
#define NL 4
#define NP 4
#define DFF 1024
#define LTOT 8500

typedef __bf16 bf16x8 __attribute__((ext_vector_type(8)));
typedef float floatx4 __attribute__((ext_vector_type(4)));

__device__ inline unsigned bpack(float a, float b) {
    __hip_bfloat16 ha = __float2bfloat16(a), hb = __float2bfloat16(b);
    unsigned short ua, ub;
    memcpy(&ua, &ha, 2); memcpy(&ub, &hb, 2);
    return (unsigned)ua | ((unsigned)ub << 16);
}

// async 16B global->LDS (wave-uniform LDS dest + lane*16; per-lane global src)
__device__ inline void gload16(const void* g, void* l) {
    __builtin_amdgcn_global_load_lds((const __attribute__((address_space(1))) void*)g,
                                     (__attribute__((address_space(3))) void*)l,
                                     16, 0, 0);
}

// ---------------- transpose+convert 6 weights (736 tiles) + bf16 prep of q/src ----------------
__global__ void transpose_all(const float* W0, const float* W1_, const float* W2_,
                              const float* W3, const float* W4, const float* W5,
                              __hip_bfloat16* T0, __hip_bfloat16* T1, __hip_bfloat16* T2,
                              __hip_bfloat16* T3, __hip_bfloat16* T4, __hip_bfloat16* T5,
                              const float* src, const float* pos,
                              __hip_bfloat16* qb, __hip_bfloat16* srcb) {
    int id = blockIdx.x;
    if (id >= 736) {
        int idx = (id - 736) * 2048 + threadIdx.x * 8;
        if (idx < LTOT * 256) {
            float4 s0 = *(const float4*)(src + idx);
            float4 s1 = *(const float4*)(src + idx + 4);
            float4 p0 = *(const float4*)(pos + idx);
            float4 p1 = *(const float4*)(pos + idx + 4);
            uint4 us, uq;
            us.x = bpack(s0.x, s0.y); us.y = bpack(s0.z, s0.w);
            us.z = bpack(s1.x, s1.y); us.w = bpack(s1.z, s1.w);
            uq.x = bpack(s0.x + p0.x, s0.y + p0.y); uq.y = bpack(s0.z + p0.z, s0.w + p0.w);
            uq.z = bpack(s1.x + p1.x, s1.y + p1.y); uq.w = bpack(s1.z + p1.z, s1.w + p1.w);
            *(uint4*)(srcb + idx) = us;
            *(uint4*)(qb + idx)  = uq;
        }
        return;
    }
    const int cum[7] = {0, 64, 96, 160, 224, 480, 736};
    int mi = 0;
    while (id >= cum[mi + 1]) mi++;
    int lid = id - cum[mi];
    const float* W; __hip_bfloat16* T; int K, N;
    switch (mi) {
        case 0: W = W0; T = T0; K = 256;  N = 256;  break;
        case 1: W = W1_; T = T1; K = 256; N = 128;  break;
        case 2: W = W2_; T = T2; K = 256; N = 256;  break;
        case 3: W = W3; T = T3; K = 256;  N = 256;  break;
        case 4: W = W4; T = T4; K = 256;  N = 1024; break;
        default: W = W5; T = T5; K = 1024; N = 256; break;
    }
    int ntx = N >> 5;
    int n0 = (lid % ntx) * 32, k0 = (lid / ntx) * 32;
    __shared__ float t[32][33];
    int tx = threadIdx.x & 31, ty = threadIdx.x >> 5;
#pragma unroll
    for (int i = 0; i < 32; i += 8)
        t[ty + i][tx] = W[(size_t)(k0 + ty + i) * N + n0 + tx];
    __syncthreads();
#pragma unroll
    for (int i = 0; i < 32; i += 8)
        T[(size_t)(n0 + ty + i) * K + k0 + tx] = __float2bfloat16(t[tx][ty + i]);
}

// ---- fused projection GEMM [Wo | Wa | Wv]: 64x64 tiles, max-TLP (r7, unchanged) ----
__global__ __launch_bounds__(256) void proj2(
    const __hip_bfloat16* __restrict__ qb, const __hip_bfloat16* __restrict__ srcb,
    const __hip_bfloat16* __restrict__ WoT, const __hip_bfloat16* __restrict__ WaT,
    const __hip_bfloat16* __restrict__ WvT,
    const float* __restrict__ bo, const float* __restrict__ ba, const float* __restrict__ bv,
    float* __restrict__ locb, float* __restrict__ attnb, __hip_bfloat16* __restrict__ valb,
    int M) {
    constexpr int BM = 64, BN = 64, BK = 64, K = 256;
    __shared__ __align__(16) __hip_bfloat16 sA[BM * BK];
    __shared__ __align__(16) __hip_bfloat16 sB[BN * BK];

    int n0 = blockIdx.x * BN;
    int m0 = blockIdx.y * BM;

    const __hip_bfloat16* BT;
    const __hip_bfloat16* A;
    const float* bias;
    int ncol0, Nout;
    float* Cf; __hip_bfloat16* Cb;
    if (n0 < 256)      { A = qb;   BT = WoT; bias = bo; ncol0 = n0;       Nout = 256; Cf = locb;  Cb = nullptr; }
    else if (n0 < 384) { A = qb;   BT = WaT; bias = ba; ncol0 = n0 - 256; Nout = 128; Cf = attnb; Cb = nullptr; }
    else               { A = srcb; BT = WvT; bias = bv; ncol0 = n0 - 384; Nout = 256; Cf = nullptr; Cb = valb; }

    int tid = threadIdx.x, wave = tid >> 6, lane = tid & 63;
    int wm = (wave >> 1) * 32, wn = (wave & 1) * 32;

    floatx4 acc[2][2];
#pragma unroll
    for (int i = 0; i < 2; i++)
#pragma unroll
        for (int j = 0; j < 2; j++)
#pragma unroll
            for (int e = 0; e < 4; e++) acc[i][j][e] = 0.f;

    int lrow = lane & 15, swz = lrow & 7;
    int scol = ((lane & 7) ^ (lane >> 3)) << 3;

    const __hip_bfloat16* aP[2];
    const __hip_bfloat16* bP[2];
#pragma unroll
    for (int i = 0; i < 2; i++) {
        int ra = m0 + i * 32 + wave * 8 + (lane >> 3); if (ra >= M) ra = M - 1;
        aP[i] = A + (size_t)ra * K + scol;
        int rb = ncol0 + i * 32 + wave * 8 + (lane >> 3);
        bP[i] = BT + (size_t)rb * K + scol;
    }
    int dOff = wave * 1024 + lane * 16;

    for (int k0 = 0; k0 < K; k0 += BK) {
#pragma unroll
        for (int i = 0; i < 2; i++) gload16(aP[i] + k0, (char*)sA + i * 4096 + dOff);
#pragma unroll
        for (int i = 0; i < 2; i++) gload16(bP[i] + k0, (char*)sB + i * 4096 + dOff);
        __syncthreads();
#pragma unroll
        for (int kk = 0; kk < 2; kk++) {
            int co = (((kk << 2) + (lane >> 4)) ^ swz) << 3;
            bf16x8 af[2], bfr[2];
#pragma unroll
            for (int tm = 0; tm < 2; tm++)
                af[tm] = *(const bf16x8*)(&sA[(wm + tm * 16 + lrow) * BK + co]);
#pragma unroll
            for (int tn = 0; tn < 2; tn++)
                bfr[tn] = *(const bf16x8*)(&sB[(wn + tn * 16 + lrow) * BK + co]);
#pragma unroll
            for (int tm = 0; tm < 2; tm++)
#pragma unroll
                for (int tn = 0; tn < 2; tn++)
                    acc[tm][tn] = __builtin_amdgcn_mfma_f32_16x16x32_bf16(af[tm], bfr[tn], acc[tm][tn], 0, 0, 0);
        }
        __syncthreads();
    }

    int lcol = lane & 15, lr4 = (lane >> 4) * 4;
#pragma unroll
    for (int tm = 0; tm < 2; tm++) {
#pragma unroll
        for (int i = 0; i < 4; i++) {
            int row = m0 + wm + tm * 16 + lr4 + i;
            if (row < M) {
#pragma unroll
                for (int tn = 0; tn < 2; tn++) {
                    int col = ncol0 + wn + tn * 16 + lcol;
                    float v = acc[tm][tn][i] + bias[col];
                    if (Cf) Cf[(size_t)row * Nout + col] = v;
                    else    Cb[(size_t)row * Nout + col] = __float2bfloat16(v);
                }
            }
        }
    }
}

// ---------------- deform core: 4 queries/block, full-TLP grid (r7, unchanged) ----------------
__global__ __launch_bounds__(256) void deform(const __hip_bfloat16* __restrict__ value,
                                              const float* __restrict__ locraw,
                                              const float* __restrict__ logits,
                                              const float* __restrict__ refp,
                                              __hip_bfloat16* __restrict__ out) {
    __shared__ float wS[4][8][16][4];
    __shared__ int   aS[4][8][16][4];
    int tid = threadIdx.x;
    int q0 = blockIdx.x * 4;

    {   // phase 1
        int sub = tid >> 6, h = (tid >> 3) & 7, t8 = tid & 7;
        int q = q0 + sub;
        const float* lg = logits + q * 128 + h * 16;
        float l0 = lg[t8], l1 = lg[t8 + 8];
        float mx = fmaxf(l0, l1);
#pragma unroll
        for (int m = 1; m < 8; m <<= 1) mx = fmaxf(mx, __shfl_xor(mx, m, 64));
        float e0 = __expf(l0 - mx), e1 = __expf(l1 - mx);
        float s = e0 + e1;
#pragma unroll
        for (int m = 1; m < 8; m <<= 1) s += __shfl_xor(s, m, 64);
        float inv = 1.f / s;

        const int starts[4] = {0, 6400, 8000, 8400};
#pragma unroll
        for (int j = 0; j < 2; j++) {
            int pp = t8 + 8 * j;
            float a = (j ? e1 : e0) * inv;
            int l = pp >> 2;
            int Wl = 80 >> l;
            float nv = (float)Wl;
            float rx = refp[q * 8 + l * 2 + 0];
            float ry = refp[q * 8 + l * 2 + 1];
            float lx = rx + locraw[q * 256 + h * 32 + pp * 2 + 0] / nv;
            float ly = ry + locraw[q * 256 + h * 32 + pp * 2 + 1] / nv;
            float x = lx * nv - 0.5f;
            float y = ly * nv - 0.5f;
            float x0f = floorf(x), y0f = floorf(y);
            float fx = x - x0f, fy = y - y0f;
            int x0 = (int)x0f, y0 = (int)y0f;
            float wts[4] = {(1.f - fx) * (1.f - fy), fx * (1.f - fy),
                            (1.f - fx) * fy,         fx * fy};
            int st = starts[l];
#pragma unroll
            for (int t = 0; t < 4; t++) {
                int xi = x0 + (t & 1), yi = y0 + (t >> 1);
                bool valid = (xi >= 0) & (xi < Wl) & (yi >= 0) & (yi < Wl);
                int xc = min(max(xi, 0), Wl - 1), yc = min(max(yi, 0), Wl - 1);
                wS[sub][h][pp][t] = valid ? wts[t] * a : 0.f;
                aS[sub][h][pp][t] = (st + yc * Wl + xc) * 512 + h * 64;
            }
        }
    }
    __syncthreads();

    // phase 2: tid = sub*64 + h*8 + l8
    int sub = tid >> 6, h = (tid >> 3) & 7, l8 = tid & 7;
    int q = q0 + sub;
    const char* vb = (const char*)value;
    int lo = l8 * 8;
    float a0 = 0.f, a1 = 0.f, a2 = 0.f, a3 = 0.f;
#pragma unroll
    for (int p = 0; p < 16; p++) {
        floatx4 w = *(const floatx4*)&wS[sub][h][p][0];
        int4 av = *(const int4*)&aS[sub][h][p][0];
#pragma unroll
        for (int t = 0; t < 4; t++) {
            int ad = (t == 0) ? av.x : (t == 1) ? av.y : (t == 2) ? av.z : av.w;
            uint2 u = *(const uint2*)(vb + ad + lo);
            float wt = w[t];
            a0 += wt * __uint_as_float(u.x << 16);
            a1 += wt * __uint_as_float(u.x & 0xffff0000u);
            a2 += wt * __uint_as_float(u.y << 16);
            a3 += wt * __uint_as_float(u.y & 0xffff0000u);
        }
    }
    uint2 o;
    o.x = bpack(a0, a1);
    o.y = bpack(a2, a3);
    *(uint2*)((char*)out + q * 512 + h * 64 + l8 * 8) = o;
}

// ---- MERGED TAIL: x1 = LN1(aob@WoutT + bout + src); h = relu(x1b@W1T + b1);
//      out = LN2(x1 + h@W2T + b2).  16 rows/block, 512 thr; LDS ~73KB -> 2 blocks/CU.
//      GEMM+LN structure identical to r8's passing ffn/deform_ln kernels.
__global__ __launch_bounds__(512) void tail(
    const __hip_bfloat16* __restrict__ aob,   // deform output [M][256] bf16
    const __hip_bfloat16* __restrict__ WoutT, const float* __restrict__ bout,
    const float* __restrict__ src,            // resid1 (f32)
    const float* __restrict__ g1, const float* __restrict__ be1,
    const __hip_bfloat16* __restrict__ W1T, const float* __restrict__ b1,
    const __hip_bfloat16* __restrict__ W2T, const float* __restrict__ b2,
    const float* __restrict__ g2, const float* __restrict__ be2,
    float* __restrict__ outf, int M) {
    __shared__ __align__(16) __hip_bfloat16 sAx[16 * 256];   // 8KB: aob, later x1b (swizzled rows)
    __shared__ __align__(16) __hip_bfloat16 H[16 * 1032];    // 33KB padded rows
    __shared__ __align__(16) __hip_bfloat16 sB[256 * 64];    // 32KB
    __shared__ float psum[8][16], psq[8][16], mS[16], rS[16];

    int tid = threadIdx.x, wave = tid >> 6, lane = tid & 63;
    int m0 = blockIdx.x * 16;
    int lrow = lane & 15, swz = lrow & 7, q2 = lane >> 4;
    int quad = lane >> 4, lcol = lane & 15;
    int swzA = (lrow & 7) << 3;
    int scolB = ((tid & 7) ^ ((tid >> 3) & 7)) << 3;

    // stage sAx = aob rows m0..m0+15 (source pre-swizzled, rule 21)
    {
        int rr = tid >> 5, cc = tid & 31;
        int gr = m0 + rr; if (gr >= M) gr = M - 1;
        int colel = (cc * 8) ^ ((rr & 7) << 3);
        gload16(aob + (size_t)gr * 256 + colel, (char*)sAx + tid * 16);
    }

    // ================= GEMM1: acc = aob @ WoutT (K=256) =================
    const __hip_bfloat16* bP[4];
#pragma unroll
    for (int i = 0; i < 4; i++)
        bP[i] = WoutT + (size_t)(i * 64 + (tid >> 3)) * 256 + scolB;

    floatx4 acc[2];
#pragma unroll
    for (int j = 0; j < 2; j++)
#pragma unroll
        for (int e = 0; e < 4; e++) acc[j][e] = 0.f;

    for (int t = 0; t < 4; t++) {
#pragma unroll
        for (int i = 0; i < 4; i++) gload16(bP[i] + t * 64, (char*)sB + i * 8192 + tid * 16);
        __syncthreads();   // t==0 also drains sAx staging
#pragma unroll
        for (int kk = 0; kk < 2; kk++) {
            int co = (((kk << 2) + q2) ^ swz) << 3;
            bf16x8 af = *(const bf16x8*)(&sAx[lrow * 256 + ((t * 64 + kk * 32 + q2 * 8) ^ swzA)]);
            bf16x8 bfr[2];
#pragma unroll
            for (int tn = 0; tn < 2; tn++)
                bfr[tn] = *(const bf16x8*)(&sB[(wave * 32 + tn * 16 + lrow) * 64 + co]);
#pragma unroll
            for (int tn = 0; tn < 2; tn++)
                acc[tn] = __builtin_amdgcn_mfma_f32_16x16x32_bf16(af, bfr[tn], acc[tn], 0, 0, 0);
        }
        __syncthreads();
    }

    // ---- LN1: x1 = LN(acc + bout + src) ----
    float v1[2][4];
#pragma unroll
    for (int i = 0; i < 4; i++) {
        int row = quad * 4 + i;
        int grow = m0 + row; if (grow >= M) grow = M - 1;
#pragma unroll
        for (int tn = 0; tn < 2; tn++) {
            int col = wave * 32 + tn * 16 + lcol;
            v1[tn][i] = acc[tn][i] + bout[col] + src[(size_t)grow * 256 + col];
        }
    }
#pragma unroll
    for (int i = 0; i < 4; i++) {
        float s = 0.f, s2 = 0.f;
#pragma unroll
        for (int tn = 0; tn < 2; tn++) { float x = v1[tn][i]; s += x; s2 += x * x; }
#pragma unroll
        for (int m = 1; m < 16; m <<= 1) {
            s  += __shfl_xor(s, m, 64);
            s2 += __shfl_xor(s2, m, 64);
        }
        if (lcol == 0) { int row = quad * 4 + i; psum[wave][row] = s; psq[wave][row] = s2; }
    }
    __syncthreads();
    if (tid < 16) {
        float s = 0.f, s2 = 0.f;
#pragma unroll
        for (int w = 0; w < 8; w++) { s += psum[w][tid]; s2 += psq[w][tid]; }
        float m = s * (1.f / 256.f);
        float var = fmaxf(s2 * (1.f / 256.f) - m * m, 0.f);
        mS[tid] = m; rS[tid] = rsqrtf(var + 1e-5f);
    }
    __syncthreads();

    float x1r[2][4];   // normalized x1 slice kept for FFN2 residual
#pragma unroll
    for (int i = 0; i < 4; i++) {
        int row = quad * 4 + i;
        float m = mS[row], r = rS[row];
#pragma unroll
        for (int tn = 0; tn < 2; tn++) {
            int col = wave * 32 + tn * 16 + lcol;
            float o = (v1[tn][i] - m) * r * g1[col] + be1[col];
            x1r[tn][i] = o;
            sAx[row * 256 + (col ^ ((row & 7) << 3))] = __float2bfloat16(o);  // x1b, swizzled
        }
    }
    // x1b writes become visible at the next __syncthreads (inside FFN1's t-loop)

    // ================= FFN1: H = relu(x1b @ W1T + b1), 4 col-chunks =================
    for (int c = 0; c < 4; c++) {
        const __hip_bfloat16* bPc[4];
#pragma unroll
        for (int i = 0; i < 4; i++)
            bPc[i] = W1T + (size_t)(c * 256 + i * 64 + (tid >> 3)) * 256 + scolB;

        floatx4 accA[2];
#pragma unroll
        for (int j = 0; j < 2; j++)
#pragma unroll
            for (int e = 0; e < 4; e++) accA[j][e] = 0.f;

        for (int t = 0; t < 4; t++) {
#pragma unroll
            for (int i = 0; i < 4; i++) gload16(bPc[i] + t * 64, (char*)sB + i * 8192 + tid * 16);
            __syncthreads();
#pragma unroll
            for (int kk = 0; kk < 2; kk++) {
                int co = (((kk << 2) + q2) ^ swz) << 3;
                bf16x8 af = *(const bf16x8*)(&sAx[lrow * 256 + ((t * 64 + kk * 32 + q2 * 8) ^ swzA)]);
                bf16x8 bfr[2];
#pragma unroll
                for (int tn = 0; tn < 2; tn++)
                    bfr[tn] = *(const bf16x8*)(&sB[(wave * 32 + tn * 16 + lrow) * 64 + co]);
#pragma unroll
                for (int tn = 0; tn < 2; tn++)
                    accA[tn] = __builtin_amdgcn_mfma_f32_16x16x32_bf16(af, bfr[tn], accA[tn], 0, 0, 0);
            }
            __syncthreads();
        }

#pragma unroll
        for (int i = 0; i < 4; i++) {
            int row = quad * 4 + i;
#pragma unroll
            for (int tn = 0; tn < 2; tn++) {
                int col = c * 256 + wave * 32 + tn * 16 + lcol;
                float v = accA[tn][i] + b1[col];
                H[row * 1032 + col] = __float2bfloat16(fmaxf(v, 0.f));
            }
        }
    }

    // ================= FFN2: out = LN2(x1 + H @ W2T + b2) =================
    const __hip_bfloat16* bP2[4];
#pragma unroll
    for (int i = 0; i < 4; i++)
        bP2[i] = W2T + (size_t)(i * 64 + (tid >> 3)) * 1024 + scolB;

    floatx4 acc2[2];
#pragma unroll
    for (int j = 0; j < 2; j++)
#pragma unroll
        for (int e = 0; e < 4; e++) acc2[j][e] = 0.f;

    for (int t = 0; t < 16; t++) {
#pragma unroll
        for (int i = 0; i < 4; i++) gload16(bP2[i] + t * 64, (char*)sB + i * 8192 + tid * 16);
        __syncthreads();   // first iter also covers H-write visibility
#pragma unroll
        for (int kk = 0; kk < 2; kk++) {
            int co = (((kk << 2) + q2) ^ swz) << 3;
            bf16x8 af = *(const bf16x8*)(&H[lrow * 1032 + t * 64 + kk * 32 + q2 * 8]);
            bf16x8 bfr[2];
#pragma unroll
            for (int tn = 0; tn < 2; tn++)
                bfr[tn] = *(const bf16x8*)(&sB[(wave * 32 + tn * 16 + lrow) * 64 + co]);
#pragma unroll
            for (int tn = 0; tn < 2; tn++)
                acc2[tn] = __builtin_amdgcn_mfma_f32_16x16x32_bf16(af, bfr[tn], acc2[tn], 0, 0, 0);
        }
        __syncthreads();
    }

    float v2[2][4];
#pragma unroll
    for (int i = 0; i < 4; i++) {
#pragma unroll
        for (int tn = 0; tn < 2; tn++) {
            int col = wave * 32 + tn * 16 + lcol;
            v2[tn][i] = acc2[tn][i] + b2[col] + x1r[tn][i];
        }
    }
#pragma unroll
    for (int i = 0; i < 4; i++) {
        float s = 0.f, s2 = 0.f;
#pragma unroll
        for (int tn = 0; tn < 2; tn++) { float x = v2[tn][i]; s += x; s2 += x * x; }
#pragma unroll
        for (int m = 1; m < 16; m <<= 1) {
            s  += __shfl_xor(s, m, 64);
            s2 += __shfl_xor(s2, m, 64);
        }
        if (lcol == 0) { int row = quad * 4 + i; psum[wave][row] = s; psq[wave][row] = s2; }
    }
    __syncthreads();
    if (tid < 16) {
        float s = 0.f, s2 = 0.f;
#pragma unroll
        for (int w = 0; w < 8; w++) { s += psum[w][tid]; s2 += psq[w][tid]; }
        float m = s * (1.f / 256.f);
        float var = fmaxf(s2 * (1.f / 256.f) - m * m, 0.f);
        mS[tid] = m; rS[tid] = rsqrtf(var + 1e-5f);
    }
    __syncthreads();

#pragma unroll
    for (int i = 0; i < 4; i++) {
        int row = quad * 4 + i;
        int grow = m0 + row;
        if (grow < M) {
            float m = mS[row], r = rS[row];
#pragma unroll
            for (int tn = 0; tn < 2; tn++) {
                int col = wave * 32 + tn * 16 + lcol;
                outf[(size_t)grow * 256 + col] = (v2[tn][i] - m) * r * g2[col] + be2[col];
            }
        }
    }
}

extern "C" void kernel_launch(void* const* d_in, const int* in_sizes, int n_in,
                              void* d_out, int out_size, void* d_ws, size_t ws_size,
                              hipStream_t stream) {
    const float* src  = (const float*)d_in[0];
    const float* pos  = (const float*)d_in[1];
    const float* refp = (const float*)d_in[2];
    const float* Wo   = (const float*)d_in[6];
    const float* bo   = (const float*)d_in[7];
    const float* Wa   = (const float*)d_in[8];
    const float* ba   = (const float*)d_in[9];
    const float* Wv   = (const float*)d_in[10];
    const float* bv   = (const float*)d_in[11];
    const float* Wout = (const float*)d_in[12];
    const float* bout = (const float*)d_in[13];
    const float* W1   = (const float*)d_in[14];
    const float* b1   = (const float*)d_in[15];
    const float* W2   = (const float*)d_in[16];
    const float* b2   = (const float*)d_in[17];
    const float* g1   = (const float*)d_in[18];
    const float* be1  = (const float*)d_in[19];
    const float* g2   = (const float*)d_in[20];
    const float* be2  = (const float*)d_in[21];
    float* out = (float*)d_out;
    char* ws = (char*)d_ws;

    // ---- workspace layout (bytes) ----
    __hip_bfloat16* WoT   = (__hip_bfloat16*)(ws + 0);         //  131072
    __hip_bfloat16* WaT   = (__hip_bfloat16*)(ws + 131072);    //   65536
    __hip_bfloat16* WvT   = (__hip_bfloat16*)(ws + 196608);    //  131072
    __hip_bfloat16* WoutT = (__hip_bfloat16*)(ws + 327680);    //  131072
    __hip_bfloat16* W1T   = (__hip_bfloat16*)(ws + 458752);    //  524288
    __hip_bfloat16* W2T   = (__hip_bfloat16*)(ws + 983040);    //  524288
    float*          locb  = (float*)(ws + 1507328);            // 8704000
    float*          attnb = (float*)(ws + 10211328);           // 4352000
    __hip_bfloat16* valb  = (__hip_bfloat16*)(ws + 14563328);  // 4352000
    __hip_bfloat16* aob   = (__hip_bfloat16*)(ws + 18915328);  // 4352000
    __hip_bfloat16* qb    = (__hip_bfloat16*)(ws + 23267328);  // 4352000
    __hip_bfloat16* srcb  = (__hip_bfloat16*)(ws + 27619328);  // 4352000 (end ~32 MB)

    transpose_all<<<736 + 1063, 256, 0, stream>>>(Wo, Wa, Wv, Wout, W1, W2,
                                                  WoT, WaT, WvT, WoutT, W1T, W2T,
                                                  src, pos, qb, srcb);

    proj2<<<dim3(10, 133), 256, 0, stream>>>(qb, srcb, WoT, WaT, WvT, bo, ba, bv,
                                             locb, attnb, valb, LTOT);

    deform<<<2125, 256, 0, stream>>>(valb, locb, attnb, refp, aob);

    tail<<<532, 512, 0, stream>>>(aob, WoutT, bout, src, g1, be1,
                                  W1T, b1, W2T, b2, g2, be2, out, LTOT);
}